// Round 1
// baseline (4390.958 us; speedup 1.0000x reference)
//
#include <hip/hip_runtime.h>
#include <math.h>

// Problem constants
#define VV   50000
#define CC0  2000
#define CC1  10000
#define ED   512
#define HD   1024
#define BBATCH 32
#define TT   128
#define HH1  256
#define HH2  64
#define SS1  8000
#define SS2  40000
#define NR   4064        // B*(T-1) = 32*127
#define G3   3072        // 3*H

// Workspace layout (offsets in floats). Total ~72.3 MB.
#define OFF_XP   0ull                      // 4064*3072 = 12,484,608
#define OFF_YS   12484608ull               // 4064*1024 =  4,161,536
#define OFF_H0   16646144ull               // 32768
#define OFF_H1   16678912ull               // 32768
#define OFF_P1   16711680ull               // 4064*256 = 1,040,384
#define OFF_P2   17752064ull               // 4064*64  =   260,096
#define OFF_SUM  18012160ull               // hsum,hsel,t1sum,t1sel,t2sum,t2sel (6*4064)
#define OFF_LOSS (OFF_SUM + 6ull*4064ull)  // 64 floats (only [0] used)
#define OFF_INT  (OFF_LOSS + 64ull)        // int region: targets,hselc,list1,list2,cnt1,cnt2

#define ZERO_N (6*4064 + 64)

// ---------------------------------------------------------------------------
// init: copy h0, zero the sum/loss region and counters
__global__ void init_k(const float* __restrict__ hidden, float* __restrict__ h0,
                       float* __restrict__ zreg, int* __restrict__ cnt1, int* __restrict__ cnt2)
{
    int i = blockIdx.x * 256 + threadIdx.x;
    if (i < BBATCH * HD) h0[i] = hidden[i];
    int zi = i - BBATCH * HD;
    if (zi >= 0 && zi < ZERO_N) zreg[zi] = 0.f;
    if (zi == ZERO_N) { *cnt1 = 0; *cnt2 = 0; }
}

// prep: targets, head sel-cols, cluster row lists
__global__ void prep_k(const int* __restrict__ x, int* __restrict__ targets,
                       int* __restrict__ hselc, int* __restrict__ list1,
                       int* __restrict__ list2, int* __restrict__ cnt1, int* __restrict__ cnt2)
{
    int n = blockIdx.x * 256 + threadIdx.x;
    if (n >= NR) return;
    int b = n / 127, t = n % 127;
    int tgt = x[b * TT + t + 1];
    targets[n] = tgt;
    hselc[n] = (tgt < CC0) ? tgt : ((tgt < CC1) ? CC0 : CC0 + 1);
    if (tgt >= CC0 && tgt < CC1) list1[atomicAdd(cnt1, 1)] = n;
    else if (tgt >= CC1)         list2[atomicAdd(cnt2, 1)] = n;
}

// ---------------------------------------------------------------------------
// GEMM: xp[r, c] = dot(emb[tok(r)], w_ih[c]) + b_ih[c]
// row r = t*32 + b ; token = x[b*128 + t]
__global__ void __launch_bounds__(256)
gemm_xp_k(const int* __restrict__ x, const float* __restrict__ emb,
          const float* __restrict__ w_ih, const float* __restrict__ b_ih,
          float* __restrict__ xp)
{
    __shared__ float smem[2 * 16 * 132];
    __shared__ int tok[128];
    float* As = smem;
    float* Ws = smem + 16 * 132;
    const int tid = threadIdx.x;
    const int rbase = blockIdx.x * 128;
    const int cbase = blockIdx.y * 128;
    const int rg = tid >> 4, cg = tid & 15;
    const int rl = tid >> 1;
    const int kk0 = (tid & 1) * 8;

    if (tid < 128) {
        int r = rbase + tid;
        tok[tid] = (r < NR) ? x[(r & 31) * TT + (r >> 5)] : -1;
    }
    __syncthreads();

    float acc[8][8];
#pragma unroll
    for (int i = 0; i < 8; i++)
#pragma unroll
        for (int j = 0; j < 8; j++) acc[i][j] = 0.f;

    for (int k0 = 0; k0 < ED; k0 += 16) {
        int tk = tok[rl];
        float4 a0 = make_float4(0,0,0,0), a1 = a0;
        if (tk >= 0) {
            const float* ap = emb + (size_t)tk * ED + k0 + kk0;
            a0 = *(const float4*)(ap);
            a1 = *(const float4*)(ap + 4);
        }
        As[(kk0+0)*132 + rl] = a0.x; As[(kk0+1)*132 + rl] = a0.y;
        As[(kk0+2)*132 + rl] = a0.z; As[(kk0+3)*132 + rl] = a0.w;
        As[(kk0+4)*132 + rl] = a1.x; As[(kk0+5)*132 + rl] = a1.y;
        As[(kk0+6)*132 + rl] = a1.z; As[(kk0+7)*132 + rl] = a1.w;

        const float* wp = w_ih + (size_t)(cbase + rl) * ED + k0 + kk0;
        float4 w0 = *(const float4*)(wp);
        float4 w1 = *(const float4*)(wp + 4);
        Ws[(kk0+0)*132 + rl] = w0.x; Ws[(kk0+1)*132 + rl] = w0.y;
        Ws[(kk0+2)*132 + rl] = w0.z; Ws[(kk0+3)*132 + rl] = w0.w;
        Ws[(kk0+4)*132 + rl] = w1.x; Ws[(kk0+5)*132 + rl] = w1.y;
        Ws[(kk0+6)*132 + rl] = w1.z; Ws[(kk0+7)*132 + rl] = w1.w;
        __syncthreads();
#pragma unroll
        for (int kk = 0; kk < 16; kk++) {
            float4 va0 = *(float4*)&As[kk*132 + rg*8];
            float4 va1 = *(float4*)&As[kk*132 + rg*8 + 4];
            float4 vw0 = *(float4*)&Ws[kk*132 + cg*8];
            float4 vw1 = *(float4*)&Ws[kk*132 + cg*8 + 4];
            float av[8] = {va0.x,va0.y,va0.z,va0.w,va1.x,va1.y,va1.z,va1.w};
            float wv[8] = {vw0.x,vw0.y,vw0.z,vw0.w,vw1.x,vw1.y,vw1.z,vw1.w};
#pragma unroll
            for (int i = 0; i < 8; i++)
#pragma unroll
                for (int j = 0; j < 8; j++) acc[i][j] += av[i] * wv[j];
        }
        __syncthreads();
    }
#pragma unroll
    for (int i = 0; i < 8; i++) {
        int r = rbase + rg*8 + i;
        if (r >= NR) continue;
#pragma unroll
        for (int j = 0; j < 8; j++) {
            int c = cbase + cg*8 + j;
            xp[(size_t)r * G3 + c] = acc[i][j] + b_ih[c];
        }
    }
}

// ---------------------------------------------------------------------------
// GEMM from ys rows (n-ordered): EPI 0 = store to outC (ldc), EPI 1 = exp-sum head
template<int EPI>
__global__ void __launch_bounds__(256)
gemm_ys_k(const float* __restrict__ ys, const float* __restrict__ W, int ncols,
          float* __restrict__ outC, int ldc,
          float* __restrict__ gsum, float* __restrict__ gsel, const int* __restrict__ selcol)
{
    __shared__ float smem[2 * 16 * 132];
    __shared__ const float* aptr[128];
    float* As = smem;
    float* Ws = smem + 16 * 132;
    const int tid = threadIdx.x;
    const int rbase = blockIdx.x * 128;
    const int cbase = blockIdx.y * 128;
    const int rg = tid >> 4, cg = tid & 15;
    const int rl = tid >> 1;
    const int kk0 = (tid & 1) * 8;

    if (tid < 128) {
        int n = rbase + tid;
        if (n < NR) {
            int t = n % 127, b = n / 127;
            aptr[tid] = ys + (size_t)(t * BBATCH + b) * HD;
        } else aptr[tid] = nullptr;
    }
    __syncthreads();

    float acc[8][8];
#pragma unroll
    for (int i = 0; i < 8; i++)
#pragma unroll
        for (int j = 0; j < 8; j++) acc[i][j] = 0.f;

    for (int k0 = 0; k0 < HD; k0 += 16) {
        const float* ap = aptr[rl];
        float4 a0 = make_float4(0,0,0,0), a1 = a0;
        if (ap) { a0 = *(const float4*)(ap + k0 + kk0); a1 = *(const float4*)(ap + k0 + kk0 + 4); }
        As[(kk0+0)*132 + rl] = a0.x; As[(kk0+1)*132 + rl] = a0.y;
        As[(kk0+2)*132 + rl] = a0.z; As[(kk0+3)*132 + rl] = a0.w;
        As[(kk0+4)*132 + rl] = a1.x; As[(kk0+5)*132 + rl] = a1.y;
        As[(kk0+6)*132 + rl] = a1.z; As[(kk0+7)*132 + rl] = a1.w;

        int c = cbase + rl;
        float4 w0 = make_float4(0,0,0,0), w1 = w0;
        if (c < ncols) {
            const float* wp = W + (size_t)c * HD + k0 + kk0;
            w0 = *(const float4*)(wp);
            w1 = *(const float4*)(wp + 4);
        }
        Ws[(kk0+0)*132 + rl] = w0.x; Ws[(kk0+1)*132 + rl] = w0.y;
        Ws[(kk0+2)*132 + rl] = w0.z; Ws[(kk0+3)*132 + rl] = w0.w;
        Ws[(kk0+4)*132 + rl] = w1.x; Ws[(kk0+5)*132 + rl] = w1.y;
        Ws[(kk0+6)*132 + rl] = w1.z; Ws[(kk0+7)*132 + rl] = w1.w;
        __syncthreads();
#pragma unroll
        for (int kk = 0; kk < 16; kk++) {
            float4 va0 = *(float4*)&As[kk*132 + rg*8];
            float4 va1 = *(float4*)&As[kk*132 + rg*8 + 4];
            float4 vw0 = *(float4*)&Ws[kk*132 + cg*8];
            float4 vw1 = *(float4*)&Ws[kk*132 + cg*8 + 4];
            float av[8] = {va0.x,va0.y,va0.z,va0.w,va1.x,va1.y,va1.z,va1.w};
            float wv[8] = {vw0.x,vw0.y,vw0.z,vw0.w,vw1.x,vw1.y,vw1.z,vw1.w};
#pragma unroll
            for (int i = 0; i < 8; i++)
#pragma unroll
                for (int j = 0; j < 8; j++) acc[i][j] += av[i] * wv[j];
        }
        __syncthreads();
    }

    if constexpr (EPI == 0) {
#pragma unroll
        for (int i = 0; i < 8; i++) {
            int r = rbase + rg*8 + i;
            if (r >= NR) continue;
#pragma unroll
            for (int j = 0; j < 8; j++) {
                int c = cbase + cg*8 + j;
                if (c < ncols) outC[(size_t)r * ldc + c] = acc[i][j];
            }
        }
    } else {
        __syncthreads();
        float* red = smem;  // 128*17 = 2176 <= 4224
#pragma unroll
        for (int i = 0; i < 8; i++) {
            int r = rbase + rg*8 + i;
            float s = 0.f;
            if (r < NR) {
                int sc = selcol[r];
#pragma unroll
                for (int j = 0; j < 8; j++) {
                    int c = cbase + cg*8 + j;
                    if (c < ncols) {
                        s += __expf(acc[i][j]);
                        if (c == sc) gsel[r] = acc[i][j];
                    }
                }
            }
            red[(rg*8 + i) * 17 + cg] = s;
        }
        __syncthreads();
        if (tid < 128) {
            int r = rbase + tid;
            if (r < NR) {
                float tot = 0.f;
#pragma unroll
                for (int q = 0; q < 16; q++) tot += red[tid * 17 + q];
                atomicAdd(&gsum[r], tot);
            }
        }
    }
}

// ---------------------------------------------------------------------------
// Tail cluster GEMM + exp-sum over compacted rows. A row = proj + n*K.
__global__ void __launch_bounds__(256)
gemm_tail_k(const float* __restrict__ Aproj, int K, const float* __restrict__ W, int ncols,
            const int* __restrict__ list, const int* __restrict__ cntp,
            const int* __restrict__ targets, int lo,
            float* __restrict__ gsum, float* __restrict__ gsel)
{
    const int cnt = *cntp;
    const int rbase = blockIdx.x * 128;
    if (rbase >= cnt) return;
    __shared__ float smem[2 * 16 * 132];
    __shared__ int rown[128];
    float* As = smem;
    float* Ws = smem + 16 * 132;
    const int tid = threadIdx.x;
    const int cbase = blockIdx.y * 128;
    const int rg = tid >> 4, cg = tid & 15;
    const int rl = tid >> 1;
    const int kk0 = (tid & 1) * 8;

    if (tid < 128) {
        int ir = rbase + tid;
        rown[tid] = (ir < cnt) ? list[ir] : -1;
    }
    __syncthreads();

    float acc[8][8];
#pragma unroll
    for (int i = 0; i < 8; i++)
#pragma unroll
        for (int j = 0; j < 8; j++) acc[i][j] = 0.f;

    for (int k0 = 0; k0 < K; k0 += 16) {
        int n = rown[rl];
        float4 a0 = make_float4(0,0,0,0), a1 = a0;
        if (n >= 0) {
            const float* ap = Aproj + (size_t)n * K + k0 + kk0;
            a0 = *(const float4*)(ap);
            a1 = *(const float4*)(ap + 4);
        }
        As[(kk0+0)*132 + rl] = a0.x; As[(kk0+1)*132 + rl] = a0.y;
        As[(kk0+2)*132 + rl] = a0.z; As[(kk0+3)*132 + rl] = a0.w;
        As[(kk0+4)*132 + rl] = a1.x; As[(kk0+5)*132 + rl] = a1.y;
        As[(kk0+6)*132 + rl] = a1.z; As[(kk0+7)*132 + rl] = a1.w;

        int c = cbase + rl;
        float4 w0 = make_float4(0,0,0,0), w1 = w0;
        if (c < ncols) {
            const float* wp = W + (size_t)c * K + k0 + kk0;
            w0 = *(const float4*)(wp);
            w1 = *(const float4*)(wp + 4);
        }
        Ws[(kk0+0)*132 + rl] = w0.x; Ws[(kk0+1)*132 + rl] = w0.y;
        Ws[(kk0+2)*132 + rl] = w0.z; Ws[(kk0+3)*132 + rl] = w0.w;
        Ws[(kk0+4)*132 + rl] = w1.x; Ws[(kk0+5)*132 + rl] = w1.y;
        Ws[(kk0+6)*132 + rl] = w1.z; Ws[(kk0+7)*132 + rl] = w1.w;
        __syncthreads();
#pragma unroll
        for (int kk = 0; kk < 16; kk++) {
            float4 va0 = *(float4*)&As[kk*132 + rg*8];
            float4 va1 = *(float4*)&As[kk*132 + rg*8 + 4];
            float4 vw0 = *(float4*)&Ws[kk*132 + cg*8];
            float4 vw1 = *(float4*)&Ws[kk*132 + cg*8 + 4];
            float av[8] = {va0.x,va0.y,va0.z,va0.w,va1.x,va1.y,va1.z,va1.w};
            float wv[8] = {vw0.x,vw0.y,vw0.z,vw0.w,vw1.x,vw1.y,vw1.z,vw1.w};
#pragma unroll
            for (int i = 0; i < 8; i++)
#pragma unroll
                for (int j = 0; j < 8; j++) acc[i][j] += av[i] * wv[j];
        }
        __syncthreads();
    }

    __syncthreads();
    float* red = smem;
#pragma unroll
    for (int i = 0; i < 8; i++) {
        int n = rown[rg*8 + i];
        float s = 0.f;
        if (n >= 0) {
            int sc = targets[n] - lo;
#pragma unroll
            for (int j = 0; j < 8; j++) {
                int c = cbase + cg*8 + j;
                if (c < ncols) {
                    s += __expf(acc[i][j]);
                    if (c == sc) gsel[n] = acc[i][j];
                }
            }
        }
        red[(rg*8 + i) * 17 + cg] = s;
    }
    __syncthreads();
    if (tid < 128) {
        int n = rown[tid];
        if (n >= 0) {
            float tot = 0.f;
#pragma unroll
            for (int q = 0; q < 16; q++) tot += red[tid * 17 + q];
            atomicAdd(&gsum[n], tot);
        }
    }
}

// ---------------------------------------------------------------------------
// One GRU step: hp = h @ w_hh^T + b_hh, gates, masked update. 256 blocks x 128 thr.
__global__ void __launch_bounds__(128)
gru_step_k(const float* __restrict__ xp_t, const float* __restrict__ hin,
           float* __restrict__ hout, const float* __restrict__ w_hh,
           const float* __restrict__ b_hh, const int* __restrict__ lengths,
           float* __restrict__ ys_t, int t)
{
    __shared__ float h_s[32 * 260];
    const int tid = threadIdx.x;
    const int b = tid & 31, jj = tid >> 5;
    const int j = blockIdx.x * 4 + jj;
    float ar = 0.f, az = 0.f, an = 0.f;
    const float* wr = w_hh + (size_t)j * HD;
    const float* wz = w_hh + (size_t)(HD + j) * HD;
    const float* wn = w_hh + (size_t)(2 * HD + j) * HD;

    for (int k0 = 0; k0 < HD; k0 += 256) {
#pragma unroll
        for (int it = 0; it < 16; it++) {
            int lin = it * 128 + tid;       // 0..2047 float4 slots
            int bb = lin >> 6;
            int kq = lin & 63;
            float4 v = *(const float4*)(hin + (size_t)bb * HD + k0 + kq * 4);
            *(float4*)&h_s[bb * 260 + kq * 4] = v;
        }
        __syncthreads();
#pragma unroll 8
        for (int kk = 0; kk < 256; kk += 4) {
            float4 hv = *(float4*)&h_s[b * 260 + kk];
            float4 r4 = *(const float4*)(wr + k0 + kk);
            float4 z4 = *(const float4*)(wz + k0 + kk);
            float4 n4 = *(const float4*)(wn + k0 + kk);
            ar += hv.x * r4.x + hv.y * r4.y + hv.z * r4.z + hv.w * r4.w;
            az += hv.x * z4.x + hv.y * z4.y + hv.z * z4.z + hv.w * z4.w;
            an += hv.x * n4.x + hv.y * n4.y + hv.z * n4.z + hv.w * n4.w;
        }
        __syncthreads();
    }

    float hr = ar + b_hh[j], hz = az + b_hh[HD + j], hn = an + b_hh[2 * HD + j];
    float xr = xp_t[(size_t)b * G3 + j];
    float xz = xp_t[(size_t)b * G3 + HD + j];
    float xn = xp_t[(size_t)b * G3 + 2 * HD + j];
    float r = 1.f / (1.f + __expf(-(xr + hr)));
    float z = 1.f / (1.f + __expf(-(xz + hz)));
    float nv = tanhf(xn + r * hn);
    float hold = hin[(size_t)b * HD + j];
    bool valid = t < (lengths[b] - 1);
    float hnew = valid ? ((1.f - z) * nv + z * hold) : hold;
    hout[(size_t)b * HD + j] = hnew;
    ys_t[(size_t)b * HD + j] = valid ? hnew : 0.f;
}

// ---------------------------------------------------------------------------
__global__ void finish_k(const float* __restrict__ hsum, const float* __restrict__ hsel,
                         const float* __restrict__ t1sum, const float* __restrict__ t1sel,
                         const float* __restrict__ t2sum, const float* __restrict__ t2sel,
                         const int* __restrict__ targets, float* __restrict__ losssum)
{
    __shared__ float red[256];
    int n = blockIdx.x * 256 + threadIdx.x;
    float lp = 0.f;
    if (n < NR) {
        lp = hsel[n] - logf(hsum[n]);
        int tgt = targets[n];
        if (tgt >= CC1)      lp += t2sel[n] - logf(t2sum[n]);
        else if (tgt >= CC0) lp += t1sel[n] - logf(t1sum[n]);
    }
    red[threadIdx.x] = lp;
    __syncthreads();
    for (int s = 128; s > 0; s >>= 1) {
        if (threadIdx.x < s) red[threadIdx.x] += red[threadIdx.x + s];
        __syncthreads();
    }
    if (threadIdx.x == 0) atomicAdd(losssum, red[0]);
}

__global__ void out_k(const float* __restrict__ losssum, const float* __restrict__ hT,
                      float* __restrict__ out)
{
    int i = blockIdx.x * 256 + threadIdx.x;
    if (i == 0) out[0] = -losssum[0] / (float)NR;
    if (i < BBATCH * HD) out[1 + i] = hT[i];
}

// ---------------------------------------------------------------------------
extern "C" void kernel_launch(void* const* d_in, const int* in_sizes, int n_in,
                              void* d_out, int out_size, void* d_ws, size_t ws_size,
                              hipStream_t stream)
{
    const int*   x       = (const int*)d_in[0];
    const int*   lengths = (const int*)d_in[1];
    const float* hidden  = (const float*)d_in[2];
    const float* emb     = (const float*)d_in[3];
    const float* w_ih    = (const float*)d_in[4];
    const float* w_hh    = (const float*)d_in[5];
    const float* b_ih    = (const float*)d_in[6];
    const float* b_hh    = (const float*)d_in[7];
    const float* head_w  = (const float*)d_in[8];
    const float* p1      = (const float*)d_in[9];
    const float* t1      = (const float*)d_in[10];
    const float* p2      = (const float*)d_in[11];
    const float* t2      = (const float*)d_in[12];

    float* ws = (float*)d_ws;
    float* xp    = ws + OFF_XP;
    float* ys    = ws + OFF_YS;
    float* h0b   = ws + OFF_H0;
    float* h1b   = ws + OFF_H1;
    float* proj1 = ws + OFF_P1;
    float* proj2 = ws + OFF_P2;
    float* hsum  = ws + OFF_SUM;
    float* hsel  = hsum + 4064;
    float* t1sum = hsel + 4064;
    float* t1sel = t1sum + 4064;
    float* t2sum = t1sel + 4064;
    float* t2sel = t2sum + 4064;
    float* losss = ws + OFF_LOSS;
    int* ib      = (int*)(ws + OFF_INT);
    int* targets = ib;
    int* hselc   = ib + 4064;
    int* list1   = ib + 2 * 4064;
    int* list2   = ib + 3 * 4064;
    int* cnt1    = ib + 4 * 4064;
    int* cnt2    = cnt1 + 1;

    float* out = (float*)d_out;

    init_k<<<224, 256, 0, stream>>>(hidden, h0b, hsum, cnt1, cnt2);
    prep_k<<<16, 256, 0, stream>>>(x, targets, hselc, list1, list2, cnt1, cnt2);

    // xp = embed(x) @ w_ih^T + b_ih   [4064 x 3072]
    gemm_xp_k<<<dim3(32, 24), 256, 0, stream>>>(x, emb, w_ih, b_ih, xp);

    // GRU recurrence, double-buffered hidden
    float* hb[2] = { h0b, h1b };
    for (int t = 0; t < TT - 1; t++) {
        gru_step_k<<<256, 128, 0, stream>>>(xp + (size_t)t * BBATCH * G3,
                                            hb[t & 1], hb[(t + 1) & 1],
                                            w_hh, b_hh, lengths,
                                            ys + (size_t)t * BBATCH * HD, t);
    }
    float* hT = hb[(TT - 1) & 1];   // after 127 steps -> h1b

    // projections (all rows; cheap)
    gemm_ys_k<0><<<dim3(32, 2), 256, 0, stream>>>(ys, p1, HH1, proj1, HH1,
                                                  nullptr, nullptr, nullptr);
    gemm_ys_k<0><<<dim3(32, 1), 256, 0, stream>>>(ys, p2, HH2, proj2, HH2,
                                                  nullptr, nullptr, nullptr);
    // head logits + exp-sum + selected logit
    gemm_ys_k<1><<<dim3(32, 16), 256, 0, stream>>>(ys, head_w, CC0 + 2, nullptr, 0,
                                                   hsum, hsel, hselc);
    // tails over compacted cluster rows
    gemm_tail_k<<<dim3(32, 63), 256, 0, stream>>>(proj1, HH1, t1, SS1, list1, cnt1,
                                                  targets, CC0, t1sum, t1sel);
    gemm_tail_k<<<dim3(32, 313), 256, 0, stream>>>(proj2, HH2, t2, SS2, list2, cnt2,
                                                   targets, CC1, t2sum, t2sel);

    finish_k<<<16, 256, 0, stream>>>(hsum, hsel, t1sum, t1sel, t2sum, t2sel,
                                     targets, losss);
    out_k<<<128, 256, 0, stream>>>(losss, hT, out);
}